// Round 7
// baseline (178.015 us; speedup 1.0000x reference)
//
#include <hip/hip_runtime.h>
#include <hip/hip_fp16.h>

#define GSZ 640
#define NIMG 320
#define MS 102400
#define NC 12
#define BETA_F 13.8551004f
#define TWOPI_F 6.2831855f
// fp16 grid scaling: G is ~1e-9..1e-10 in the reference's un-normalized KB
// convention (weights ~1e4 each restore it). Store G*2^24 in fp16, fold 2^-24
// into the interp weights -- cancels exactly, keeps fp16 in its normal range.
#define GSC 16777216.0f
#define GSC_INV 5.9604645e-8f

// ---------- Bessel I0 (Abramowitz & Stegun 9.8.1 / 9.8.2, rel err < 2e-7) ----------
__device__ __forceinline__ float i0f(float x) {
    float ax = fabsf(x);
    if (ax < 3.75f) {
        float t = ax * (1.0f / 3.75f);
        t *= t;
        return 1.0f + t * (3.5156229f + t * (3.0899424f + t * (1.2067492f +
                     t * (0.2659732f + t * (0.0360768f + t * 0.0045813f)))));
    } else {
        float t = 3.75f / ax;
        float p = 0.39894228f + t * (0.01328592f + t * (0.00225319f + t * (-0.00157565f +
                  t * (0.00916281f + t * (-0.02057706f + t * (0.02635537f +
                  t * (-0.01647633f + t * 0.00392377f)))))));
        return p * expf(ax) / sqrtf(ax);
    }
}

// Kaiser-Bessel kernel, support |u| <= 3 (J=6)
__device__ __forceinline__ float kbval(float u) {
    float mm = fabsf(u) * (1.0f / 3.0f);
    float s = 1.0f - mm * mm;
    s = s > 0.0f ? s : 0.0f;
    float v = i0f(BETA_F * sqrtf(s)) * (1.0f / 6.0f);
    return (mm <= 1.0f) ? v : 0.0f;
}

// image-domain apodization correction at pixel n (0..319)
__device__ __forceinline__ float apodval(int n) {
    float s = 0.0f;
    #pragma unroll
    for (int j = -3; j <= 3; ++j) {
        s += kbval((float)j) * cosf((TWOPI_F * (float)j * ((float)n - 160.0f)) / 640.0f);
    }
    return 1.0f / s;
}

__device__ __forceinline__ float2 cmul(float2 a, float2 w) {
    return make_float2(a.x * w.x - a.y * w.y, a.x * w.y + a.y * w.x);
}

// Stockham DIF radix-4 stage: 160 butterflies, call with t < 160.
__device__ __forceinline__ void radix4_stage(const float2* src, float2* dst,
                                             int t, int s, int n) {
    int p = t / s, q = t - p * s;
    int m = n >> 2;
    float2 a0 = src[q + s * p];
    float2 a1 = src[q + s * (p + m)];
    float2 a2 = src[q + s * (p + 2 * m)];
    float2 a3 = src[q + s * (p + 3 * m)];
    float2 e = make_float2(a0.x + a2.x, a0.y + a2.y);
    float2 f = make_float2(a1.x + a3.x, a1.y + a3.y);
    float2 g = make_float2(a0.x - a2.x, a0.y - a2.y);
    float2 h = make_float2(a1.x - a3.x, a1.y - a3.y);
    float2 B0 = make_float2(e.x + f.x, e.y + f.y);
    float2 B2 = make_float2(e.x - f.x, e.y - f.y);
    float2 mih = make_float2(h.y, -h.x);                 // -i*h
    float2 B1 = make_float2(g.x + mih.x, g.y + mih.y);
    float2 B3 = make_float2(g.x - mih.x, g.y - mih.y);
    float ang = (-TWOPI_F) * (float)p / (float)n;
    float s1, c1, s2, c2, s3, c3;
    __sincosf(ang, &s1, &c1);
    __sincosf(2.0f * ang, &s2, &c2);
    __sincosf(3.0f * ang, &s3, &c3);
    dst[q + s * (4 * p)]     = B0;
    dst[q + s * (4 * p + 1)] = cmul(B1, make_float2(c1, s1));
    dst[q + s * (4 * p + 2)] = cmul(B2, make_float2(c2, s2));
    dst[q + s * (4 * p + 3)] = cmul(B3, make_float2(c3, s3));
}

// ---------- 640-point FFT: radix-5, 3x radix-4 (LDS), final radix-2 in regs ----------
// Engine-local: bA/bB are this engine's 640-elem buffers, t in [0,320).
// __syncthreads() is block-wide; co-resident engines stay in lockstep.
__device__ void fft640(float2* bA, float2* bB, int t, float2* olo, float2* ohi) {
    __syncthreads();   // bA ready
    if (t < 128) {
        float2 aj[5];
        #pragma unroll
        for (int j = 0; j < 5; ++j) aj[j] = bA[t + 128 * j];
        const float wr[5] = {1.0f, 0.30901699f, -0.80901699f, -0.80901699f, 0.30901699f};
        const float wi[5] = {0.0f, -0.95105652f, -0.58778525f, 0.58778525f, 0.95105652f};
        #pragma unroll
        for (int r = 0; r < 5; ++r) {
            float br = aj[0].x, bi = aj[0].y;
            #pragma unroll
            for (int j = 1; j < 5; ++j) {
                int k = (j * r) % 5;
                br += aj[j].x * wr[k] - aj[j].y * wi[k];
                bi += aj[j].x * wi[k] + aj[j].y * wr[k];
            }
            float sn, cs;
            __sincosf((-TWOPI_F / 640.0f) * (float)(t * r), &sn, &cs);
            bB[5 * t + r] = cmul(make_float2(br, bi), make_float2(cs, sn));
        }
    }
    __syncthreads();
    if (t < 160) radix4_stage(bB, bA, t, 5, 128);
    __syncthreads();
    if (t < 160) radix4_stage(bA, bB, t, 20, 32);
    __syncthreads();
    if (t < 160) radix4_stage(bB, bA, t, 80, 8);
    __syncthreads();
    float2 a = bA[t], b = bA[t + 320];
    *olo = make_float2(a.x + b.x, a.y + b.y);
    *ohi = make_float2(a.x - b.x, a.y - b.y);
}

// ---------- pass A: row FFT, 2 rows/block (2 engines x 320 threads) ----------
// apod fused. Writes R[c][ri][q] coalesced (rows ri0, ri0+1 contiguous).
__global__ __launch_bounds__(640)
void passA_kernel(const float* __restrict__ img_r, const float* __restrict__ img_i,
                  const float* __restrict__ sm_r, const float* __restrict__ sm_i,
                  float2* __restrict__ R) {
    __shared__ float2 bA[2][GSZ], bB[2][GSZ];
    int e = threadIdx.x >= 320;
    int t = threadIdx.x - 320 * e;
    int ri = 2 * blockIdx.x + e, c = blockIdx.y;
    int h = (ri < 160) ? ri + 160 : ri - 160;
    int w = (t < 160) ? t + 160 : t - 160;
    float scale = apodval(h) * apodval(w) * (1.0f / 640.0f);  // incl. 1/sqrt(G1*G2)
    float xr = img_r[h * NIMG + w];
    float xi = img_i[h * NIMG + w];
    float sr = sm_r[(c * NIMG + h) * NIMG + w];
    float si = sm_i[(c * NIMG + h) * NIMG + w];
    float vr = (xr * sr - xi * si) * scale;
    float vi = (xr * si + xi * sr) * scale;
    int vnz = (t < 160) ? t : t + 320;   // ifftshifted column position
    int vz  = (t < 160) ? t + 320 : t;
    bA[e][vnz] = make_float2(vr, vi);
    bA[e][vz]  = make_float2(0.0f, 0.0f);
    float2 lo, hi;
    fft640(bA[e], bB[e], t, &lo, &hi);
    float2* out = R + (c * 320 + ri) * GSZ;
    out[t] = lo;
    out[t + 320] = hi;
}

// ---------- pass T: tiled transpose R[c][ri][q] -> Rt[c][q][ri] ----------
__global__ __launch_bounds__(256)
void passT_kernel(const float2* __restrict__ R, float2* __restrict__ Rt) {
    __shared__ float2 tile[32][33];
    int q0 = blockIdx.x * 32, r0 = blockIdx.y * 32, c = blockIdx.z;
    int tx = threadIdx.x & 31, ty = threadIdx.x >> 5;  // 32 x 8
    #pragma unroll
    for (int k = 0; k < 4; ++k) {
        int r = ty + 8 * k;
        tile[r][tx] = R[(c * 320 + r0 + r) * GSZ + q0 + tx];
    }
    __syncthreads();
    #pragma unroll
    for (int k = 0; k < 4; ++k) {
        int r = ty + 8 * k;  // q_sub
        Rt[(c * GSZ + q0 + r) * 320 + r0 + tx] = tile[tx][r];
    }
}

// ---------- pass B (fused B1+B2): column FFT for ALL coils of one q ----------
// 640 blocks (one per q) x 640 threads (2 engines). 6 serial coil-pair rounds;
// results staged as scaled fp16 in LDS Gs[u][c] (stride-13 pad), then one
// fully contiguous 30720B store of G[q][.][.]  -- skips the F HBM round-trip.
__global__ __launch_bounds__(640)
void passB_kernel(const float2* __restrict__ Rt, unsigned int* __restrict__ G) {
    __shared__ float2 bA[2][GSZ], bB[2][GSZ];
    __shared__ unsigned int Gs[GSZ * 13];   // [u][c], stride 13 words (no conflicts)
    int q = blockIdx.x;
    int e = threadIdx.x >= 320;
    int t = threadIdx.x - 320 * e;
    int rnz = (t < 160) ? t : t + 320;   // ifftshifted row position
    int rz  = (t < 160) ? t + 320 : t;
    for (int rnd = 0; rnd < 6; ++rnd) {
        int c = 2 * rnd + e;
        float2 val = Rt[(c * GSZ + q) * 320 + t];
        __syncthreads();   // prior round's bA readers are different threads
        bA[e][rnz] = val;
        bA[e][rz]  = make_float2(0.0f, 0.0f);
        float2 lo, hi;
        fft640(bA[e], bB[e], t, &lo, &hi);
        __half2 hlo = __float22half2_rn(make_float2(lo.x * GSC, lo.y * GSC));
        __half2 hhi = __float22half2_rn(make_float2(hi.x * GSC, hi.y * GSC));
        Gs[t * 13 + c]         = *(const unsigned int*)&hlo;
        Gs[(t + 320) * 13 + c] = *(const unsigned int*)&hhi;
    }
    __syncthreads();
    unsigned int* out = G + q * (GSZ * NC);   // 7680 uint words
    #pragma unroll
    for (int j = 0; j < 12; ++j) {
        int i = threadIdx.x + 640 * j;
        int u = i / 12, c = i - 12 * u;
        out[i] = Gs[u * 13 + c];
    }
}

// ---------- KB tap weights + wrapped indices ----------
__device__ __forceinline__ void taps(float om, float* w, int* idx) {
    float t = fmodf((om * 640.0f) / TWOPI_F, 640.0f);
    if (t < 0.0f) t += 640.0f;
    float base = floorf(t);
    float frac = t - base;
    int ib = (int)base;
    #pragma unroll
    for (int j = 0; j < 6; ++j) {
        w[j] = kbval(frac + (float)(2 - j));  // u = t - (base + j - 2)
        int k = ib + j - 2;
        if (k < 0) k += GSZ;
        if (k >= GSZ) k -= GSZ;
        idx[j] = k;
    }
}

struct __align__(8) h2x2 { __half2 a, b; };  // 2 coils: (re,im),(re,im)

// ---------- interpolation: 6 lanes per sample, 2 coils per lane, fp16 grid ----------
__global__ __launch_bounds__(256)
void interp_kernel(const float* __restrict__ kt, const h2x2* __restrict__ Gp,
                   float2* __restrict__ out) {
    int tid = blockIdx.x * 256 + threadIdx.x;   // 614400 = 2400*256 exactly
    int m = tid / 6;
    int p = tid - 6 * m;                        // coil pair index 0..5
    float w1[6], w2[6];
    int iu[6], iv[6];
    taps(kt[m], w1, iu);        // dim 0 -> u (row frequency)
    taps(kt[MS + m], w2, iv);   // dim 1 -> v (col frequency)
    #pragma unroll
    for (int j = 0; j < 6; ++j) w2[j] *= GSC_INV;   // undo the fp16 grid scaling
    float a0r = 0.0f, a0i = 0.0f, a1r = 0.0f, a1i = 0.0f;
    #pragma unroll
    for (int j2 = 0; j2 < 6; ++j2) {
        int rb = iv[j2] * (GSZ * 6) + p;        // h2x2 index base for this v-row
        float b2 = w2[j2];
        #pragma unroll
        for (int j1 = 0; j1 < 6; ++j1) {
            h2x2 g = Gp[rb + iu[j1] * 6];
            float2 f0 = __half22float2(g.a);
            float2 f1 = __half22float2(g.b);
            float ww = b2 * w1[j1];
            a0r = fmaf(ww, f0.x, a0r);
            a0i = fmaf(ww, f0.y, a0i);
            a1r = fmaf(ww, f1.x, a1r);
            a1i = fmaf(ww, f1.y, a1i);
        }
    }
    out[(2 * p) * MS + m]     = make_float2(a0r, a0i);
    out[(2 * p + 1) * MS + m] = make_float2(a1r, a1i);
}

extern "C" void kernel_launch(void* const* d_in, const int* in_sizes, int n_in,
                              void* d_out, int out_size, void* d_ws, size_t ws_size,
                              hipStream_t stream) {
    const float* img_r = (const float*)d_in[0];
    const float* img_i = (const float*)d_in[1];
    const float* sm_r  = (const float*)d_in[2];
    const float* sm_i  = (const float*)d_in[3];
    const float* kt    = (const float*)d_in[4];

    // ws layout (~39MB): [R 19.66M][Rt 19.66M]; G(fp16, 19.66M) overlays R
    // lifetimes: R(passA) -> Rt(passT; R dead) -> G(passB; overlays R)
    char* base = (char*)d_ws;
    float2* R  = (float2*)base;                                // 12*320*640*8
    float2* Rt = (float2*)(base + 19660800);                   // 12*640*320*8
    unsigned int* G = (unsigned int*)base;                     // 640*640*12*4 (fp16 pairs)

    passA_kernel<<<dim3(160, NC), 640, 0, stream>>>(img_r, img_i, sm_r, sm_i, R);
    passT_kernel<<<dim3(20, 10, NC), 256, 0, stream>>>(R, Rt);
    passB_kernel<<<GSZ, 640, 0, stream>>>(Rt, G);
    interp_kernel<<<2400, 256, 0, stream>>>(kt, (const h2x2*)G, (float2*)d_out);
}

// Round 9
// 169.231 us; speedup vs baseline: 1.0519x; 1.0519x over previous
//
#include <hip/hip_runtime.h>
#include <hip/hip_fp16.h>

#define GSZ 640
#define NIMG 320
#define MS 102400
#define NC 12
#define BETA_F 13.8551004f
#define TWOPI_F 6.2831855f
// fp16 grid scaling: G is ~1e-9..1e-10 in the reference's un-normalized KB
// convention (weights ~1e4 each restore it). Scale by 2^24 ONCE in passT;
// the linear FFT carries it; fold 2^-24 into the interp weights.
#define GSC 16777216.0f
#define GSC_INV 5.9604645e-8f

typedef float nfloat2 __attribute__((ext_vector_type(2)));  // for nontemporal stores

// ---------- Bessel I0 (Abramowitz & Stegun 9.8.1 / 9.8.2, rel err < 2e-7) ----------
__device__ __forceinline__ float i0f(float x) {
    float ax = fabsf(x);
    if (ax < 3.75f) {
        float t = ax * (1.0f / 3.75f);
        t *= t;
        return 1.0f + t * (3.5156229f + t * (3.0899424f + t * (1.2067492f +
                     t * (0.2659732f + t * (0.0360768f + t * 0.0045813f)))));
    } else {
        float t = 3.75f / ax;
        float p = 0.39894228f + t * (0.01328592f + t * (0.00225319f + t * (-0.00157565f +
                  t * (0.00916281f + t * (-0.02057706f + t * (0.02635537f +
                  t * (-0.01647633f + t * 0.00392377f)))))));
        return p * expf(ax) / sqrtf(ax);
    }
}

// Kaiser-Bessel kernel, support |u| <= 3 (J=6)
__device__ __forceinline__ float kbval(float u) {
    float mm = fabsf(u) * (1.0f / 3.0f);
    float s = 1.0f - mm * mm;
    s = s > 0.0f ? s : 0.0f;
    float v = i0f(BETA_F * sqrtf(s)) * (1.0f / 6.0f);
    return (mm <= 1.0f) ? v : 0.0f;
}

// image-domain apodization correction at pixel n (0..319)
__device__ __forceinline__ float apodval(int n) {
    float s = 0.0f;
    #pragma unroll
    for (int j = -3; j <= 3; ++j) {
        s += kbval((float)j) * cosf((TWOPI_F * (float)j * ((float)n - 160.0f)) / 640.0f);
    }
    return 1.0f / s;
}

__device__ __forceinline__ float2 cmul(float2 a, float2 w) {
    return make_float2(a.x * w.x - a.y * w.y, a.x * w.y + a.y * w.x);
}

// Stockham DIF radix-4 stage: 160 butterflies, call with t < 160.
__device__ __forceinline__ void radix4_stage(const float2* src, float2* dst,
                                             int t, int s, int n) {
    int p = t / s, q = t - p * s;
    int m = n >> 2;
    float2 a0 = src[q + s * p];
    float2 a1 = src[q + s * (p + m)];
    float2 a2 = src[q + s * (p + 2 * m)];
    float2 a3 = src[q + s * (p + 3 * m)];
    float2 e = make_float2(a0.x + a2.x, a0.y + a2.y);
    float2 f = make_float2(a1.x + a3.x, a1.y + a3.y);
    float2 g = make_float2(a0.x - a2.x, a0.y - a2.y);
    float2 h = make_float2(a1.x - a3.x, a1.y - a3.y);
    float2 B0 = make_float2(e.x + f.x, e.y + f.y);
    float2 B2 = make_float2(e.x - f.x, e.y - f.y);
    float2 mih = make_float2(h.y, -h.x);                 // -i*h
    float2 B1 = make_float2(g.x + mih.x, g.y + mih.y);
    float2 B3 = make_float2(g.x - mih.x, g.y - mih.y);
    float ang = (-TWOPI_F) * (float)p / (float)n;
    float s1, c1, s2, c2, s3, c3;
    __sincosf(ang, &s1, &c1);
    __sincosf(2.0f * ang, &s2, &c2);
    __sincosf(3.0f * ang, &s3, &c3);
    dst[q + s * (4 * p)]     = B0;
    dst[q + s * (4 * p + 1)] = cmul(B1, make_float2(c1, s1));
    dst[q + s * (4 * p + 2)] = cmul(B2, make_float2(c2, s2));
    dst[q + s * (4 * p + 3)] = cmul(B3, make_float2(c3, s3));
}

// ---------- 640-point FFT: radix-5, 3x radix-4 (LDS), final radix-2 in regs ----------
// Engine-local: bA/bB are this engine's 640-elem buffers, t in [0,320).
// __syncthreads() is block-wide; co-resident engines stay in lockstep.
__device__ void fft640(float2* bA, float2* bB, int t, float2* olo, float2* ohi) {
    __syncthreads();   // bA ready
    if (t < 128) {
        float2 aj[5];
        #pragma unroll
        for (int j = 0; j < 5; ++j) aj[j] = bA[t + 128 * j];
        const float wr[5] = {1.0f, 0.30901699f, -0.80901699f, -0.80901699f, 0.30901699f};
        const float wi[5] = {0.0f, -0.95105652f, -0.58778525f, 0.58778525f, 0.95105652f};
        #pragma unroll
        for (int r = 0; r < 5; ++r) {
            float br = aj[0].x, bi = aj[0].y;
            #pragma unroll
            for (int j = 1; j < 5; ++j) {
                int k = (j * r) % 5;
                br += aj[j].x * wr[k] - aj[j].y * wi[k];
                bi += aj[j].x * wi[k] + aj[j].y * wr[k];
            }
            float sn, cs;
            __sincosf((-TWOPI_F / 640.0f) * (float)(t * r), &sn, &cs);
            bB[5 * t + r] = cmul(make_float2(br, bi), make_float2(cs, sn));
        }
    }
    __syncthreads();
    if (t < 160) radix4_stage(bB, bA, t, 5, 128);
    __syncthreads();
    if (t < 160) radix4_stage(bA, bB, t, 20, 32);
    __syncthreads();
    if (t < 160) radix4_stage(bB, bA, t, 80, 8);
    __syncthreads();
    float2 a = bA[t], b = bA[t + 320];
    *olo = make_float2(a.x + b.x, a.y + b.y);
    *ohi = make_float2(a.x - b.x, a.y - b.y);
}

// ---------- pass A: row FFT, 2 rows/block (2 engines x 320 threads) ----------
// apod fused. Writes R[c][ri][q] coalesced (fp32).
__global__ __launch_bounds__(640)
void passA_kernel(const float* __restrict__ img_r, const float* __restrict__ img_i,
                  const float* __restrict__ sm_r, const float* __restrict__ sm_i,
                  float2* __restrict__ R) {
    __shared__ float2 bA[2][GSZ], bB[2][GSZ];
    int e = threadIdx.x >= 320;
    int t = threadIdx.x - 320 * e;
    int ri = 2 * blockIdx.x + e, c = blockIdx.y;
    int h = (ri < 160) ? ri + 160 : ri - 160;
    int w = (t < 160) ? t + 160 : t - 160;
    float scale = apodval(h) * apodval(w) * (1.0f / 640.0f);  // incl. 1/sqrt(G1*G2)
    float xr = img_r[h * NIMG + w];
    float xi = img_i[h * NIMG + w];
    float sr = sm_r[(c * NIMG + h) * NIMG + w];
    float si = sm_i[(c * NIMG + h) * NIMG + w];
    float vr = (xr * sr - xi * si) * scale;
    float vi = (xr * si + xi * sr) * scale;
    int vnz = (t < 160) ? t : t + 320;   // ifftshifted column position
    int vz  = (t < 160) ? t + 320 : t;
    bA[e][vnz] = make_float2(vr, vi);
    bA[e][vz]  = make_float2(0.0f, 0.0f);
    float2 lo, hi;
    fft640(bA[e], bB[e], t, &lo, &hi);
    float2* out = R + (c * 320 + ri) * GSZ;
    out[t] = lo;
    out[t + 320] = hi;
}

// ---------- pass T: transpose R[c][ri][q] -> Rt[c][q][ri], scale, fp16 ----------
__global__ __launch_bounds__(256)
void passT_kernel(const float2* __restrict__ R, unsigned int* __restrict__ Rt) {
    __shared__ float2 tile[32][33];
    int q0 = blockIdx.x * 32, r0 = blockIdx.y * 32, c = blockIdx.z;
    int tx = threadIdx.x & 31, ty = threadIdx.x >> 5;  // 32 x 8
    #pragma unroll
    for (int k = 0; k < 4; ++k) {
        int r = ty + 8 * k;
        tile[r][tx] = R[(c * 320 + r0 + r) * GSZ + q0 + tx];
    }
    __syncthreads();
    #pragma unroll
    for (int k = 0; k < 4; ++k) {
        int r = ty + 8 * k;  // q_sub
        float2 v = tile[tx][r];
        __half2 hv = __float22half2_rn(make_float2(v.x * GSC, v.y * GSC));
        Rt[(c * GSZ + q0 + r) * 320 + r0 + tx] = *(const unsigned int*)&hv;
    }
}

// ---------- pass B1: column FFT, 2 q/block; fp16 in, fp16 out (scaled) ----------
__global__ __launch_bounds__(640)
void passB1_kernel(const unsigned int* __restrict__ Rt, unsigned int* __restrict__ F) {
    __shared__ float2 bA[2][GSZ], bB[2][GSZ];
    int e = threadIdx.x >= 320;
    int t = threadIdx.x - 320 * e;
    int q0 = 2 * blockIdx.x, c = blockIdx.y;
    // engine e handles q = q0+e; combined read is one contiguous 640-word run
    unsigned int raw = Rt[(c * GSZ + q0) * 320 + threadIdx.x];
    float2 val = __half22float2(*(const __half2*)&raw);
    int rnz = (t < 160) ? t : t + 320;   // ifftshifted row position
    int rz  = (t < 160) ? t + 320 : t;
    bA[e][rnz] = val;
    bA[e][rz]  = make_float2(0.0f, 0.0f);
    float2 lo, hi;
    fft640(bA[e], bB[e], t, &lo, &hi);
    __half2 hlo = __float22half2_rn(lo);
    __half2 hhi = __float22half2_rn(hi);
    unsigned int* out = F + (c * GSZ + q0 + e) * GSZ;
    out[t]       = *(const unsigned int*)&hlo;
    out[t + 320] = *(const unsigned int*)&hhi;
}

// ---------- pass B2: pure uint shuffle F[c][q][u] -> G[q][u][c] ----------
// One block = (q, half of u). Writes 3840 words (15360B) contiguous via uint4.
__global__ __launch_bounds__(320)
void passB2_kernel(const unsigned int* __restrict__ F, unsigned int* __restrict__ G) {
    __shared__ unsigned int Ls[NC][321];
    int q = blockIdx.x, u0 = blockIdx.y * 320, t = threadIdx.x;
    #pragma unroll
    for (int c = 0; c < NC; ++c)
        Ls[c][t] = F[(c * GSZ + q) * GSZ + u0 + t];
    __syncthreads();
    uint4* out4 = (uint4*)(G + (q * GSZ + u0) * NC);  // 960 uint4
    #pragma unroll
    for (int j = 0; j < 3; ++j) {
        int k = t + 320 * j;
        int w = 4 * k;
        uint4 v;
        v.x = Ls[(w)     % 12][(w)     / 12];
        v.y = Ls[(w + 1) % 12][(w + 1) / 12];
        v.z = Ls[(w + 2) % 12][(w + 2) / 12];
        v.w = Ls[(w + 3) % 12][(w + 3) / 12];
        out4[k] = v;
    }
}

// ---------- KB tap weights + wrapped indices ----------
__device__ __forceinline__ void taps(float om, float* w, int* idx) {
    float t = fmodf((om * 640.0f) / TWOPI_F, 640.0f);
    if (t < 0.0f) t += 640.0f;
    float base = floorf(t);
    float frac = t - base;
    int ib = (int)base;
    #pragma unroll
    for (int j = 0; j < 6; ++j) {
        w[j] = kbval(frac + (float)(2 - j));  // u = t - (base + j - 2)
        int k = ib + j - 2;
        if (k < 0) k += GSZ;
        if (k >= GSZ) k -= GSZ;
        idx[j] = k;
    }
}

struct __align__(8) h2x2 { __half2 a, b; };  // 2 coils: (re,im),(re,im)

// ---------- interpolation: 6 lanes per sample, 2 coils per lane, fp16 grid ----------
__global__ __launch_bounds__(256)
void interp_kernel(const float* __restrict__ kt, const h2x2* __restrict__ Gp,
                   float* __restrict__ out) {
    int tid = blockIdx.x * 256 + threadIdx.x;   // 614400 = 2400*256 exactly
    int m = tid / 6;
    int p = tid - 6 * m;                        // coil pair index 0..5
    float w1[6], w2[6];
    int iu[6], iv[6];
    taps(kt[m], w1, iu);        // dim 0 -> u (row frequency)
    taps(kt[MS + m], w2, iv);   // dim 1 -> v (col frequency)
    #pragma unroll
    for (int j = 0; j < 6; ++j) w2[j] *= GSC_INV;   // undo the fp16 grid scaling
    float a0r = 0.0f, a0i = 0.0f, a1r = 0.0f, a1i = 0.0f;
    #pragma unroll
    for (int j2 = 0; j2 < 6; ++j2) {
        int rb = iv[j2] * (GSZ * 6) + p;        // h2x2 index base for this v-row
        float b2 = w2[j2];
        #pragma unroll
        for (int j1 = 0; j1 < 6; ++j1) {
            h2x2 g = Gp[rb + iu[j1] * 6];
            float2 f0 = __half22float2(g.a);
            float2 f1 = __half22float2(g.b);
            float ww = b2 * w1[j1];
            a0r = fmaf(ww, f0.x, a0r);
            a0i = fmaf(ww, f0.y, a0i);
            a1r = fmaf(ww, f1.x, a1r);
            a1i = fmaf(ww, f1.y, a1i);
        }
    }
    // nontemporal: don't evict G from L2 for the 4.9MB output
    nfloat2* o0 = (nfloat2*)(out + 2 * ((2 * p) * MS + m));
    nfloat2* o1 = (nfloat2*)(out + 2 * ((2 * p + 1) * MS + m));
    nfloat2 v0 = {a0r, a0i};
    nfloat2 v1 = {a1r, a1i};
    __builtin_nontemporal_store(v0, o0);
    __builtin_nontemporal_store(v1, o1);
}

extern "C" void kernel_launch(void* const* d_in, const int* in_sizes, int n_in,
                              void* d_out, int out_size, void* d_ws, size_t ws_size,
                              hipStream_t stream) {
    const float* img_r = (const float*)d_in[0];
    const float* img_i = (const float*)d_in[1];
    const float* sm_r  = (const float*)d_in[2];
    const float* sm_i  = (const float*)d_in[3];
    const float* kt    = (const float*)d_in[4];

    // ws layout (~49MB): [R fp32 19.66M][Rt fp16 9.83M][F fp16 19.66M];
    // G (fp16, 19.66M) overlays R (dead after passT).
    char* base = (char*)d_ws;
    float2*       R  = (float2*)base;                          // 12*320*640*8
    unsigned int* Rt = (unsigned int*)(base + 19660800);       // 12*640*320*4
    unsigned int* F  = (unsigned int*)(base + 29491200);       // 12*640*640*4
    unsigned int* G  = (unsigned int*)base;                    // 640*640*12*4

    passA_kernel<<<dim3(160, NC), 640, 0, stream>>>(img_r, img_i, sm_r, sm_i, R);
    passT_kernel<<<dim3(20, 10, NC), 256, 0, stream>>>(R, Rt);
    passB1_kernel<<<dim3(320, NC), 640, 0, stream>>>(Rt, F);
    passB2_kernel<<<dim3(GSZ, 2), 320, 0, stream>>>(F, G);
    interp_kernel<<<2400, 256, 0, stream>>>(kt, (const h2x2*)G, (float*)d_out);
}